// Round 1
// baseline (322.893 us; speedup 1.0000x reference)
//
#include <hip/hip_runtime.h>

#define D 256

typedef float f32x4 __attribute__((ext_vector_type(4)));
typedef short short8 __attribute__((ext_vector_type(8)));
typedef __bf16 bf16x8 __attribute__((ext_vector_type(8)));

static __device__ __forceinline__ short f2bs(float f) {
    __bf16 b = (__bf16)f;
    return __builtin_bit_cast(short, b);
}

// ---------------- precompute kernels (run every call; deterministic) ----------------

__global__ void pre_bc(const float* __restrict__ b_agg, const float* __restrict__ We1,
                       const float* __restrict__ be1, float* __restrict__ bc)
{
    int j = threadIdx.x;
    float acc = be1[j];
    for (int k = 0; k < D; ++k)
        acc += 2.f * b_agg[k] * We1[k * D + j];
    bc[j] = acc;
}

// WcT[j][i] = sum_k (W_agg[i][k] + W_agg[i+256][k] ... careful: Ws[i][k]) -- see below
// Ws[i][k] = W_agg[i*D+k] + W_agg[(i+D)*D+k]; Wc[i][j] = sum_k Ws[i][k]*We1[k][j]
__global__ void pre_wct(const float* __restrict__ W_agg, const float* __restrict__ We1,
                        short* __restrict__ WcT)
{
    __shared__ float wsrow[D];
    int i = blockIdx.x, j = threadIdx.x;
    wsrow[j] = W_agg[i * D + j] + W_agg[(i + D) * D + j];
    __syncthreads();
    float acc = 0.f;
    for (int k = 0; k < D; ++k)
        acc += wsrow[k] * We1[k * D + j];
    WcT[j * D + i] = f2bs(acc);
}

__global__ void pre_wn1t(const float* __restrict__ Wn1, short* __restrict__ Wn1T)
{
    int i = blockIdx.x, j = threadIdx.x;
    Wn1T[j * D + i] = f2bs(Wn1[i * D + j]);
}

__global__ void pre_w2t(const float* __restrict__ We2, const float* __restrict__ Wn2,
                        short* __restrict__ We2T, short* __restrict__ Wn2T)
{
    int k = threadIdx.x;
    for (int c = 0; c < 16; ++c) {
        float ve = (c < 5) ? We2[k * 5 + c] : 0.f;
        float vn = (c < 2) ? Wn2[k * 2 + c] : 0.f;
        We2T[c * D + k] = f2bs(ve);
        Wn2T[c * D + k] = f2bs(vn);
    }
}

// ---------------- fused  (GEMM1 -> bias -> relu -> GEMM2 -> bias)  ----------------
// MODE 0: rows = node_feat rows            -> out[n][ncols]
// MODE 1: rows = feat[pair[2e]] + feat[pair[2e+1]]
// Block: 256 threads = 4 waves; wave owns 32 rows (2 M-frags); 128 rows/block.
// GEMM1: K=256, Ncols=256 (16 N-tiles), mfma_f32_16x16x32_bf16.
// h (128x256 bf16) staged in XOR-swizzled LDS, then GEMM2 vs 16-col padded W2T.
template<int MODE>
__global__ __launch_bounds__(256, 2)
void fused_mlp(const float* __restrict__ feat,
               const int* __restrict__ pair,
               const short* __restrict__ W1T,   // [256][256] bf16 bits, transposed (col-major weight)
               const float* __restrict__ bias1, // [256]
               const short* __restrict__ W2T,   // [16][256] bf16 bits, zero-padded cols
               const float* __restrict__ bias2, // [ncols]
               float* __restrict__ out,
               int nrows, int ncols)
{
    __shared__ short hl[128 * D];   // 64 KB

    const int tid = threadIdx.x;
    const int lane = tid & 63;
    const int w = tid >> 6;
    const int l15 = lane & 15;
    const int g = lane >> 4;
    const int rowblk = blockIdx.x * 128 + w * 32;

    // per-frag source row pointers (clamped for the ragged node tail)
    const float* ap0[2];
    const float* ap1[2];
#pragma unroll
    for (int f = 0; f < 2; ++f) {
        int r = rowblk + f * 16 + l15;
        if (r > nrows - 1) r = nrows - 1;
        if constexpr (MODE == 0) {
            ap0[f] = feat + (size_t)r * D;
            ap1[f] = nullptr;
        } else {
            ap0[f] = feat + (size_t)pair[2 * r] * D;
            ap1[f] = feat + (size_t)pair[2 * r + 1] * D;
        }
    }

    f32x4 acc[2][16];
#pragma unroll
    for (int f = 0; f < 2; ++f)
#pragma unroll
        for (int t = 0; t < 16; ++t)
            acc[f][t] = f32x4{0.f, 0.f, 0.f, 0.f};

#pragma unroll
    for (int ks = 0; ks < 8; ++ks) {
        const int k0 = ks * 32 + g * 8;
        short8 af[2];
#pragma unroll
        for (int f = 0; f < 2; ++f) {
            const float4* p0 = reinterpret_cast<const float4*>(ap0[f] + k0);
            float4 x0 = p0[0], x1 = p0[1];
            if constexpr (MODE == 1) {
                const float4* p1 = reinterpret_cast<const float4*>(ap1[f] + k0);
                float4 y0 = p1[0], y1 = p1[1];
                x0.x += y0.x; x0.y += y0.y; x0.z += y0.z; x0.w += y0.w;
                x1.x += y1.x; x1.y += y1.y; x1.z += y1.z; x1.w += y1.w;
            }
            bf16x8 bv = {(__bf16)x0.x, (__bf16)x0.y, (__bf16)x0.z, (__bf16)x0.w,
                         (__bf16)x1.x, (__bf16)x1.y, (__bf16)x1.z, (__bf16)x1.w};
            af[f] = __builtin_bit_cast(short8, bv);
        }
#pragma unroll
        for (int t = 0; t < 16; ++t) {
            short8 bw = *reinterpret_cast<const short8*>(W1T + ((t * 16 + l15) * D + k0));
            acc[0][t] = __builtin_amdgcn_mfma_f32_16x16x32_bf16(af[0], bw, acc[0][t], 0, 0, 0);
            acc[1][t] = __builtin_amdgcn_mfma_f32_16x16x32_bf16(af[1], bw, acc[1][t], 0, 0, 0);
        }
    }

    // bias + relu -> h in LDS (bf16), XOR-swizzled 16B chunks to kill the
    // 512B-row-stride 16-way bank conflict on the GEMM2 ds_read_b128s.
#pragma unroll
    for (int t = 0; t < 16; ++t) {
        const int col = t * 16 + l15;
        const float b = bias1[col];
        const int chunk = col >> 3;
#pragma unroll
        for (int f = 0; f < 2; ++f) {
#pragma unroll
            for (int r = 0; r < 4; ++r) {
                const int rl = w * 32 + f * 16 + g * 4 + r;
                float v = acc[f][t][r] + b;
                v = fmaxf(v, 0.f);
                hl[rl * D + ((chunk ^ (rl & 7)) << 3) + (col & 7)] = f2bs(v);
            }
        }
    }

    __syncthreads();

    // GEMM2: h(32x256) @ W2(256x16-padded)
    f32x4 acc2[2];
    acc2[0] = f32x4{0.f, 0.f, 0.f, 0.f};
    acc2[1] = f32x4{0.f, 0.f, 0.f, 0.f};
#pragma unroll
    for (int ks = 0; ks < 8; ++ks) {
        const int k0 = ks * 32 + g * 8;
        const int chunk = k0 >> 3;
        short8 bw = *reinterpret_cast<const short8*>(W2T + (l15 * D + k0));
#pragma unroll
        for (int f = 0; f < 2; ++f) {
            const int rl = w * 32 + f * 16 + l15;
            short8 ah = *reinterpret_cast<const short8*>(&hl[rl * D + ((chunk ^ (rl & 7)) << 3)]);
            acc2[f] = __builtin_amdgcn_mfma_f32_16x16x32_bf16(ah, bw, acc2[f], 0, 0, 0);
        }
    }

    if (l15 < ncols) {
        const float b2 = bias2[l15];
#pragma unroll
        for (int f = 0; f < 2; ++f) {
#pragma unroll
            for (int r = 0; r < 4; ++r) {
                const int grow = rowblk + f * 16 + g * 4 + r;
                if (grow < nrows)
                    out[(size_t)grow * ncols + l15] = acc2[f][r] + b2;
            }
        }
    }
}

// ---------------- launch ----------------

extern "C" void kernel_launch(void* const* d_in, const int* in_sizes, int n_in,
                              void* d_out, int out_size, void* d_ws, size_t ws_size,
                              hipStream_t stream)
{
    const float* node_feat = (const float*)d_in[0];
    const int*   pair_idx  = (const int*)d_in[1];
    const float* W_agg     = (const float*)d_in[2];
    const float* b_agg     = (const float*)d_in[3];
    const float* We1       = (const float*)d_in[4];
    const float* be1       = (const float*)d_in[5];
    const float* We2       = (const float*)d_in[6];
    const float* be2       = (const float*)d_in[7];
    const float* Wn1       = (const float*)d_in[8];
    const float* bn1       = (const float*)d_in[9];
    const float* Wn2       = (const float*)d_in[10];
    const float* bn2       = (const float*)d_in[11];

    const int N = in_sizes[0] / D;   // 100000
    const int E = in_sizes[1] / 2;   // 262144

    float* out = (float*)d_out;
    char*  ws  = (char*)d_ws;

    short* WcT  = (short*)(ws + 0);        // 128 KB
    short* Wn1T = (short*)(ws + 131072);   // 128 KB
    short* We2T = (short*)(ws + 262144);   // 8 KB
    short* Wn2T = (short*)(ws + 270336);   // 8 KB
    float* bc   = (float*)(ws + 278528);   // 1 KB

    pre_bc<<<1, 256, 0, stream>>>(b_agg, We1, be1, bc);
    pre_wct<<<D, 256, 0, stream>>>(W_agg, We1, WcT);
    pre_wn1t<<<D, 256, 0, stream>>>(Wn1, Wn1T);
    pre_w2t<<<1, 256, 0, stream>>>(We2, Wn2, We2T, Wn2T);

    // node path: out[0 .. N*2)
    fused_mlp<0><<<(N + 127) / 128, 256, 0, stream>>>(
        node_feat, nullptr, Wn1T, bn1, Wn2T, bn2, out, N, 2);

    // edge path: out[N*2 .. N*2 + E*5)
    fused_mlp<1><<<E / 128, 256, 0, stream>>>(
        node_feat, pair_idx, WcT, bc, We2T, be2, out + (size_t)2 * N, E, 5);
}